// Round 3
// baseline (398.008 us; speedup 1.0000x reference)
//
#include <hip/hip_runtime.h>
#include <hip/hip_bf16.h>

// Max-margin (hinge) criterion — fused block-per-row.
//
// Key idea vs R1 (latency-bound at 16% HBM) and R2 (two passes, extra
// traffic): a 256-thread block owns one row and each thread issues ALL its
// loads up front (2x int4 target + 2x float4 cossim over the SAME 8 columns).
// The thread holding the one-hot hit already has the correct similarity in
// its registers -> no gather, no shuffle-broadcast chain; one LDS scalar +
// one barrier. Both arrays are read exactly once.

constexpr int   kC      = 2048;
constexpr float kMargin = 0.1f;

__global__ __launch_bounds__(256) void max_margin_fused(
    const float* __restrict__ cossim,
    const int*   __restrict__ target,
    float*       __restrict__ out,
    float inv_n)
{
    const int row = blockIdx.x;
    const int tid = threadIdx.x;
    const size_t base = (size_t)row * kC;

    const int4*   t4 = (const int4*)(target + base);
    const float4* c4 = (const float4*)(cossim + base);

    // Issue all four independent 16B loads immediately (max MLP, one wait).
    int4   t0 = t4[tid];
    int4   t1 = t4[tid + 256];
    float4 c0 = c4[tid];
    float4 c1 = c4[tid + 256];

    __shared__ float s_sim;

    // Exactly one thread in the block finds the one-hot 1; it already holds
    // the matching cossim element in registers.
    if (t0.x | t0.y | t0.z | t0.w)
        s_sim = t0.x ? c0.x : (t0.y ? c0.y : (t0.z ? c0.z : c0.w));
    if (t1.x | t1.y | t1.z | t1.w)
        s_sim = t1.x ? c1.x : (t1.y ? c1.y : (t1.z ? c1.z : c1.w));
    __syncthreads();

    const float sim = s_sim;

    float s = 0.0f;
    s += fmaxf(kMargin + c0.x - sim, 0.0f);
    s += fmaxf(kMargin + c0.y - sim, 0.0f);
    s += fmaxf(kMargin + c0.z - sim, 0.0f);
    s += fmaxf(kMargin + c0.w - sim, 0.0f);
    s += fmaxf(kMargin + c1.x - sim, 0.0f);
    s += fmaxf(kMargin + c1.y - sim, 0.0f);
    s += fmaxf(kMargin + c1.z - sim, 0.0f);
    s += fmaxf(kMargin + c1.w - sim, 0.0f);

    // The correct-choice term equals exactly kMargin and the reference zeroes
    // it; remove it once per row.
    if (tid == 0) s -= kMargin;

    // wave reduce (64 lanes)
    #pragma unroll
    for (int o = 32; o > 0; o >>= 1)
        s += __shfl_xor(s, o);

    // block reduce across 4 waves + one atomic per block
    __shared__ float ws[4];
    const int lane = tid & 63;
    const int wib  = tid >> 6;
    if (lane == 0) ws[wib] = s;
    __syncthreads();
    if (tid == 0) {
        float b = ws[0] + ws[1] + ws[2] + ws[3];
        atomicAdd(out, b * inv_n);
    }
}

extern "C" void kernel_launch(void* const* d_in, const int* in_sizes, int n_in,
                              void* d_out, int out_size, void* d_ws, size_t ws_size,
                              hipStream_t stream)
{
    const float* cossim = (const float*)d_in[0];
    const int*   target = (const int*)d_in[1];
    float*       out    = (float*)d_out;

    const int nrows = in_sizes[0] / kC;          // 16384

    // d_out is poisoned with 0xAA before every launch — zero it (graph-legal).
    hipMemsetAsync(out, 0, sizeof(float), stream);

    max_margin_fused<<<nrows, 256, 0, stream>>>(cossim, target, out,
                                                1.0f / (float)nrows);
}

// Round 4
// 289.112 us; speedup vs baseline: 1.3767x; 1.3767x over previous
//
#include <hip/hip_runtime.h>
#include <hip/hip_bf16.h>

// Max-margin (hinge) criterion — two copy-kernel-shaped streaming passes.
//
// Evidence so far: harness fill kernels sustain 6.9 TB/s writes; our read
// passes only hit ~2.3 TB/s because each thread had at most 8 loads in
// flight with dependency fences between phases (R1), or a block barrier
// right after the loads (R3). This version makes both passes flat, fully
// unrolled, 8x16B independent loads per thread issued back-to-back, no
// barriers/waits until all loads are in flight.
//
//   Pass A: scan target (int4); hitting thread gathers correct_sim[row].
//   Pass B: flat hinge over cossim (float4) + L1-hot csim[row] lookups,
//           per-thread accumulate -> wave -> block -> one atomic per block.

constexpr int   kC      = 2048;
constexpr float kMargin = 0.1f;
constexpr int   kBatch  = 8;          // 16B-chunks per thread, fully unrolled

// ---------------- Pass A: find correct similarity per row ----------------
__global__ __launch_bounds__(256) void find_correct_sim(
    const float* __restrict__ cossim,
    const int4*  __restrict__ target4,
    float*       __restrict__ csim)
{
    const int tid = threadIdx.x;
    const size_t blockBase = (size_t)blockIdx.x * (kBatch * 256);   // int4 units

    // 8 independent 16B loads, all in flight before any use.
    int4 v[kBatch];
    #pragma unroll
    for (int k = 0; k < kBatch; ++k)
        v[k] = target4[blockBase + k * 256 + tid];

    #pragma unroll
    for (int k = 0; k < kBatch; ++k) {
        int4 t = v[k];
        if ((t.x | t.y | t.z | t.w) != 0) {          // rare: one-hot hit
            size_t f   = blockBase + k * 256 + tid;  // int4 index
            size_t e   = f * 4;                      // element index
            int    row = (int)(e >> 11);             // / 2048
            int    col = (int)(e & (kC - 1));
            const float* cr = cossim + ((size_t)row << 11);
            float s = t.x ? cr[col]     :
                      t.y ? cr[col + 1] :
                      t.z ? cr[col + 2] : cr[col + 3];
            csim[row] = s;
        }
    }
}

// ---------------- Pass B: flat hinge sum ----------------
__global__ __launch_bounds__(256) void hinge_sum(
    const float4* __restrict__ cossim4,
    const float*  __restrict__ csim,
    float*        __restrict__ out,
    float inv_n)
{
    const int tid = threadIdx.x;
    const size_t blockBase = (size_t)blockIdx.x * (kBatch * 256);   // float4 units

    // 16 independent loads in flight: 8 cossim float4 + 8 csim scalars
    // (csim is 64 KB -> L1/L2-hot; addresses are index-computed, no data dep).
    float4 v[kBatch];
    float  sim[kBatch];
    #pragma unroll
    for (int k = 0; k < kBatch; ++k) {
        size_t f = blockBase + k * 256 + tid;
        v[k]   = cossim4[f];
        sim[k] = csim[f >> 9];      // row = (f*4) >> 11 = f >> 9
    }

    float s = 0.0f;
    #pragma unroll
    for (int k = 0; k < kBatch; ++k) {
        float m = kMargin - sim[k];
        s += fmaxf(m + v[k].x, 0.0f);
        s += fmaxf(m + v[k].y, 0.0f);
        s += fmaxf(m + v[k].z, 0.0f);
        s += fmaxf(m + v[k].w, 0.0f);
    }

    // wave reduce (64 lanes)
    #pragma unroll
    for (int o = 32; o > 0; o >>= 1)
        s += __shfl_xor(s, o);

    // block reduce (4 waves) + one atomic per block
    __shared__ float ws[4];
    const int lane = tid & 63;
    const int wib  = tid >> 6;
    if (lane == 0) ws[wib] = s;
    __syncthreads();
    if (tid == 0) {
        float b   = ws[0] + ws[1] + ws[2] + ws[3];
        float add = b * inv_n;
        // every row's correct-choice term is exactly kMargin and the
        // reference zeroes it: mean drops by exactly kMargin overall.
        if (blockIdx.x == 0) add -= kMargin;
        atomicAdd(out, add);
    }
}

extern "C" void kernel_launch(void* const* d_in, const int* in_sizes, int n_in,
                              void* d_out, int out_size, void* d_ws, size_t ws_size,
                              hipStream_t stream)
{
    const float* cossim = (const float*)d_in[0];
    const int*   target = (const int*)d_in[1];
    float*       out    = (float*)d_out;
    float*       csim   = (float*)d_ws;            // nrows floats of scratch

    const int nrows  = in_sizes[0] / kC;           // 16384
    const int total4 = in_sizes[1] / 4;            // 8388608 int4 chunks
    const int blocksA = total4 / (kBatch * 256);   // 4096
    const int blocksB = (in_sizes[0] / 4) / (kBatch * 256);  // 4096

    // d_out is poisoned with 0xAA before every launch — zero it (graph-legal).
    hipMemsetAsync(out, 0, sizeof(float), stream);

    find_correct_sim<<<blocksA, 256, 0, stream>>>(cossim, (const int4*)target, csim);
    hinge_sum<<<blocksB, 256, 0, stream>>>((const float4*)cossim, csim, out,
                                           1.0f / (float)nrows);
}

// Round 5
// 278.601 us; speedup vs baseline: 1.4286x; 1.0377x over previous
//
#include <hip/hip_runtime.h>
#include <hip/hip_bf16.h>

// Max-margin (hinge) criterion — single fused streaming pass, NO atomics.
//
// Evidence: R3 (16384 same-address atomicAdds) vs R1 (4096) differ by
// ~118 us => ~9.6 ns per serialized atomic. The atomic drain, not load MLP,
// was the hidden cost (R4's load batching was exactly neutral). This version:
//   - block owns 4 rows; each thread issues 8 int4 (target) + 8 float4
//     (cossim) loads over the same flat range up front;
//   - the one-hot hit thread already holds the correct similarity in
//     registers -> LDS s_sim[4], one barrier;
//   - block partial -> plain store to d_ws[blockIdx] (no atomics);
//   - tiny final kernel reduces 4096 partials and writes the mean.

constexpr int   kC      = 2048;
constexpr float kMargin = 0.1f;
constexpr int   kBatch  = 8;     // 16B chunks per thread => 4 rows per block

__global__ __launch_bounds__(256) void max_margin_main(
    const float4* __restrict__ cossim4,
    const int4*   __restrict__ target4,
    float*        __restrict__ partials)
{
    const int tid = threadIdx.x;
    const size_t base = (size_t)blockIdx.x * (kBatch * 256);   // 16B-chunk units

    // Issue all 16 independent 16B loads back-to-back.
    int4   t[kBatch];
    float4 c[kBatch];
    #pragma unroll
    for (int k = 0; k < kBatch; ++k) {
        size_t g = base + k * 256 + tid;
        t[k] = target4[g];
        c[k] = cossim4[g];
    }

    // Phase 1: hit thread publishes the correct similarity for its row.
    // Local row for chunk k is the compile-time constant k>>1
    // (k*256+tid in [0,2048), row = that >> 9).
    __shared__ float s_sim[4];
    #pragma unroll
    for (int k = 0; k < kBatch; ++k) {
        if ((t[k].x | t[k].y | t[k].z | t[k].w) != 0) {
            float v = t[k].x ? c[k].x : (t[k].y ? c[k].y
                    : (t[k].z ? c[k].z : c[k].w));
            s_sim[k >> 1] = v;
        }
    }
    __syncthreads();

    // Phase 2: hinge accumulate (cossim already in registers).
    float s = 0.0f;
    #pragma unroll
    for (int k = 0; k < kBatch; ++k) {
        float m = kMargin - s_sim[k >> 1];
        s += fmaxf(m + c[k].x, 0.0f);
        s += fmaxf(m + c[k].y, 0.0f);
        s += fmaxf(m + c[k].z, 0.0f);
        s += fmaxf(m + c[k].w, 0.0f);
    }

    // wave reduce (64 lanes)
    #pragma unroll
    for (int o = 32; o > 0; o >>= 1)
        s += __shfl_xor(s, o);

    // block reduce (4 waves) -> ONE plain store per block, no atomic
    __shared__ float ws[4];
    const int lane = tid & 63;
    const int wib  = tid >> 6;
    if (lane == 0) ws[wib] = s;
    __syncthreads();
    if (tid == 0)
        partials[blockIdx.x] = ws[0] + ws[1] + ws[2] + ws[3];
}

// Final reduce: 4096 partials -> scalar mean (also subtracts the
// correct-choice term, which is exactly kMargin per row).
__global__ __launch_bounds__(256) void final_reduce(
    const float* __restrict__ partials,
    float*       __restrict__ out,
    int nparts, float inv_n)
{
    const int tid = threadIdx.x;
    float s = 0.0f;
    for (int i = tid; i < nparts; i += 256)
        s += partials[i];

    #pragma unroll
    for (int o = 32; o > 0; o >>= 1)
        s += __shfl_xor(s, o);

    __shared__ float ws[4];
    const int lane = tid & 63;
    const int wib  = tid >> 6;
    if (lane == 0) ws[wib] = s;
    __syncthreads();
    if (tid == 0)
        out[0] = (ws[0] + ws[1] + ws[2] + ws[3]) * inv_n - kMargin;
}

extern "C" void kernel_launch(void* const* d_in, const int* in_sizes, int n_in,
                              void* d_out, int out_size, void* d_ws, size_t ws_size,
                              hipStream_t stream)
{
    const float* cossim = (const float*)d_in[0];
    const int*   target = (const int*)d_in[1];
    float*       out    = (float*)d_out;
    float*       parts  = (float*)d_ws;

    const int nrows  = in_sizes[0] / kC;                 // 16384
    const int blocks = in_sizes[0] / (kBatch * 256 * 4); // 4096

    max_margin_main<<<blocks, 256, 0, stream>>>(
        (const float4*)cossim, (const int4*)target, parts);
    final_reduce<<<1, 256, 0, stream>>>(parts, out, blocks,
                                        1.0f / (float)nrows);
}

// Round 6
// 249.963 us; speedup vs baseline: 1.5923x; 1.1146x over previous
//
#include <hip/hip_runtime.h>
#include <hip/hip_bf16.h>

// Max-margin (hinge) criterion — fused streaming pass with NONTEMPORAL loads.
//
// Evidence: four structurally different kernels (R1/R2/R4/R5) all plateau at
// ~2.5 TB/s read (268 MB / ~100 us) while harness fills sustain 7 TB/s
// writes. Reads are concurrency-capped (~38 lines/CU in flight by the
// latency arithmetic) — suspected per-CU L1 (TCP) miss-tracking. Streaming
// data has zero reuse, so bypass L1 via __builtin_nontemporal_load (nt bit).
// Everything else is identical to R5 for a clean A/B on this one lever.

constexpr int   kC      = 2048;
constexpr float kMargin = 0.1f;
constexpr int   kBatch  = 8;     // 16B chunks per thread => 4 rows per block

typedef float f32x4 __attribute__((ext_vector_type(4)));
typedef int   i32x4 __attribute__((ext_vector_type(4)));

__global__ __launch_bounds__(256) void max_margin_main(
    const f32x4* __restrict__ cossim4,
    const i32x4* __restrict__ target4,
    float*       __restrict__ partials)
{
    const int tid = threadIdx.x;
    const size_t base = (size_t)blockIdx.x * (kBatch * 256);   // 16B-chunk units

    // Issue all 16 independent 16B nontemporal loads back-to-back.
    i32x4 t[kBatch];
    f32x4 c[kBatch];
    #pragma unroll
    for (int k = 0; k < kBatch; ++k) {
        size_t g = base + k * 256 + tid;
        t[k] = __builtin_nontemporal_load(&target4[g]);
        c[k] = __builtin_nontemporal_load(&cossim4[g]);
    }

    // Phase 1: hit thread publishes the correct similarity for its row.
    // Local row for chunk k is the compile-time constant k>>1.
    __shared__ float s_sim[4];
    #pragma unroll
    for (int k = 0; k < kBatch; ++k) {
        if ((t[k].x | t[k].y | t[k].z | t[k].w) != 0) {
            float v = t[k].x ? c[k].x : (t[k].y ? c[k].y
                    : (t[k].z ? c[k].z : c[k].w));
            s_sim[k >> 1] = v;
        }
    }
    __syncthreads();

    // Phase 2: hinge accumulate (cossim already in registers).
    float s = 0.0f;
    #pragma unroll
    for (int k = 0; k < kBatch; ++k) {
        float m = kMargin - s_sim[k >> 1];
        s += fmaxf(m + c[k].x, 0.0f);
        s += fmaxf(m + c[k].y, 0.0f);
        s += fmaxf(m + c[k].z, 0.0f);
        s += fmaxf(m + c[k].w, 0.0f);
    }

    // wave reduce (64 lanes)
    #pragma unroll
    for (int o = 32; o > 0; o >>= 1)
        s += __shfl_xor(s, o);

    // block reduce (4 waves) -> ONE plain store per block, no atomic
    __shared__ float ws[4];
    const int lane = tid & 63;
    const int wib  = tid >> 6;
    if (lane == 0) ws[wib] = s;
    __syncthreads();
    if (tid == 0)
        partials[blockIdx.x] = ws[0] + ws[1] + ws[2] + ws[3];
}

// Final reduce: 4096 partials -> scalar mean (subtracting the correct-choice
// term, which is exactly kMargin per row).
__global__ __launch_bounds__(256) void final_reduce(
    const float* __restrict__ partials,
    float*       __restrict__ out,
    int nparts, float inv_n)
{
    const int tid = threadIdx.x;
    float s = 0.0f;
    for (int i = tid; i < nparts; i += 256)
        s += partials[i];

    #pragma unroll
    for (int o = 32; o > 0; o >>= 1)
        s += __shfl_xor(s, o);

    __shared__ float ws[4];
    const int lane = tid & 63;
    const int wib  = tid >> 6;
    if (lane == 0) ws[wib] = s;
    __syncthreads();
    if (tid == 0)
        out[0] = (ws[0] + ws[1] + ws[2] + ws[3]) * inv_n - kMargin;
}

extern "C" void kernel_launch(void* const* d_in, const int* in_sizes, int n_in,
                              void* d_out, int out_size, void* d_ws, size_t ws_size,
                              hipStream_t stream)
{
    const float* cossim = (const float*)d_in[0];
    const int*   target = (const int*)d_in[1];
    float*       out    = (float*)d_out;
    float*       parts  = (float*)d_ws;

    const int nrows  = in_sizes[0] / kC;                 // 16384
    const int blocks = in_sizes[0] / (kBatch * 256 * 4); // 4096

    max_margin_main<<<blocks, 256, 0, stream>>>(
        (const f32x4*)cossim, (const i32x4*)target, parts);
    final_reduce<<<1, 256, 0, stream>>>(parts, out, blocks,
                                        1.0f / (float)nrows);
}